// Round 5
// baseline (697.234 us; speedup 1.0000x reference)
//
#include <hip/hip_runtime.h>
#include <hip/hip_bf16.h>
#include <math.h>

// GraphEncoder: 3x GCNConv (relu) -> global_mean_pool -> two linear heads.
// N=100000, E=1600000, G=2048, feats 10->128->256->256->64(x2)
//
// Round-5 strategy:
//  - fill_csr col write: __builtin_nontemporal_store. Round-4 counters showed
//    WRITE_SIZE=103MB for a 6.4MB col array (1.6M scattered 4B writes x 64B
//    dirty lines). nt bypasses L2 write-allocate.
//  - launch fusion 19 -> 12 kernels: setup(init+WT), hist(deg+batch),
//    scan_all(row_ptr+cursor+dis+goff in one pass), fill_csr+scale0.
//  - MFMA transforms / bf16 aggs unchanged from round 4.

#define THREADS 256

typedef __attribute__((ext_vector_type(8))) short bf16x8;
typedef __attribute__((ext_vector_type(4))) float f32x4;

// ---------------- fused setup: deg=1, gcnt=0, W2T, W3T ----------------
__global__ void setup_kernel(int* deg, int* gcnt,
                             const float* __restrict__ W2, __hip_bfloat16* __restrict__ W2T,
                             const float* __restrict__ W3, __hip_bfloat16* __restrict__ W3T,
                             int n, int g) {
    int i = blockIdx.x * blockDim.x + threadIdx.x;
    if (i < n) deg[i] = 1;                       // self-loop
    int r1 = i - n;
    if (r1 >= 0 && r1 < g) gcnt[r1] = 0;
    int r2 = i - n - g;
    if (r2 >= 0 && r2 < 128 * 256) {
        int k = r2 >> 8, c = r2 & 255;
        W2T[c * 128 + k] = __float2bfloat16(W2[r2]);
    }
    int r3 = i - n - g - 128 * 256;
    if (r3 >= 0 && r3 < 256 * 256) {
        int k = r3 >> 8, c = r3 & 255;
        W3T[c * 256 + k] = __float2bfloat16(W3[r3]);
    }
}

// ---------------- fused histograms: indegree + graph sizes ----------------
__global__ void hist_kernel(const int* __restrict__ dst, int* deg, int e,
                            const int* __restrict__ batch, int* gcnt, int n) {
    int i = blockIdx.x * blockDim.x + threadIdx.x;
    if (i < e) {
        atomicAdd(&deg[dst[i]], 1);
    } else {
        int j = i - e;
        if (j < n) atomicAdd(&gcnt[batch[j]], 1);
    }
}

// ---------------- fused scans ----------------
// phase over `in` (minus sub) -> exclusive scan in `out` (out[n]=total);
// optionally also writes cursor[i]=out[i] and dis[i]=rsqrt(in[i]).
__device__ void scan_phase(const int* __restrict__ in, int* __restrict__ out,
                           int n, int sub, int* wsum,
                           int* __restrict__ cursor, float* __restrict__ dis) {
    int carry = 0;
    const int lane = threadIdx.x & 63;
    const int wid = threadIdx.x >> 6;
    for (int base = 0; base < n; base += 4096) {
        int i0 = base + threadIdx.x * 4;
        int v[4];
#pragma unroll
        for (int q = 0; q < 4; ++q) {
            int i = i0 + q;
            v[q] = (i < n) ? (in[i] - sub) : 0;
        }
        int tsum = v[0] + v[1] + v[2] + v[3];
        int incl = tsum;
#pragma unroll
        for (int off = 1; off < 64; off <<= 1) {
            int t = __shfl_up(incl, off, 64);
            if (lane >= off) incl += t;
        }
        if (lane == 63) wsum[wid] = incl;
        __syncthreads();
        int wbase = 0;
        for (int w = 0; w < wid; ++w) wbase += wsum[w];
        int pos = incl - tsum + wbase + carry;
#pragma unroll
        for (int q = 0; q < 4; ++q) {
            int i = i0 + q;
            if (i < n) {
                out[i] = pos;
                if (cursor) cursor[i] = pos;
                if (dis) dis[i] = rsqrtf((float)(v[q] + sub));
            }
            pos += v[q];
        }
        int tot = 0;
        for (int w = 0; w < 16; ++w) tot += wsum[w];
        carry += tot;
        __syncthreads();
    }
    if (threadIdx.x == 0) out[n] = carry;
}

__global__ __launch_bounds__(1024) void scan_all_kernel(
        const int* deg, int* row_ptr, int* cursor, float* dis, int n,
        const int* gcnt, int* goff, int g) {
    __shared__ int wsum[16];
    scan_phase(deg, row_ptr, n, 1, wsum, cursor, dis);   // indeg scan + dis + cursor
    __syncthreads();
    scan_phase(gcnt, goff, g, 0, wsum, nullptr, nullptr);
}

// ---------------- fused CSR fill (nt store) + S0 = x*dis ----------------
__global__ void fill_scale_kernel(const int* __restrict__ src, const int* __restrict__ dst,
                                  int* cursor, int* __restrict__ col,
                                  const float* __restrict__ x, const float* __restrict__ dis,
                                  float* __restrict__ F0, int e, int n10) {
    int i = blockIdx.x * blockDim.x + threadIdx.x;
    if (i < e) {
        int d = dst[i];
        int pos = atomicAdd(&cursor[d], 1);
        __builtin_nontemporal_store(src[i], &col[pos]);
    } else {
        int j = i - e;
        if (j < n10) F0[j] = x[j] * dis[j / 10];
    }
}

// ---------------- agg over 10-col f32 rows (16 lanes/node) ----------------
__global__ __launch_bounds__(THREADS) void agg10_kernel(
        const float* __restrict__ S, const int* __restrict__ row_ptr,
        const int* __restrict__ col, const float* __restrict__ dis,
        float* __restrict__ out, int n) {
    int node = blockIdx.x * 16 + threadIdx.x / 16;
    if (node >= n) return;
    int lane = threadIdx.x % 16;
    bool act = lane < 10;
    float acc = act ? S[(size_t)node * 10 + lane] : 0.f;
    int s = row_ptr[node], e = row_ptr[node + 1];
    int p = s;
    for (; p + 4 <= e; p += 4) {
        int j[4];
#pragma unroll
        for (int q = 0; q < 4; ++q) j[q] = col[p + q];
        float v[4];
#pragma unroll
        for (int q = 0; q < 4; ++q) v[q] = act ? S[(size_t)j[q] * 10 + lane] : 0.f;
        acc += v[0] + v[1] + v[2] + v[3];
    }
    for (; p < e; ++p) {
        int j = col[p];
        if (act) acc += S[(size_t)j * 10 + lane];
    }
    if (act) out[(size_t)node * 10 + lane] = acc * dis[node];
}

// ---------------- bf16 helpers ----------------
__device__ __forceinline__ void acc8(float* acc, uint4 v) {
    acc[0] += __uint_as_float(v.x << 16);
    acc[1] += __uint_as_float(v.x & 0xffff0000u);
    acc[2] += __uint_as_float(v.y << 16);
    acc[3] += __uint_as_float(v.y & 0xffff0000u);
    acc[4] += __uint_as_float(v.z << 16);
    acc[5] += __uint_as_float(v.z & 0xffff0000u);
    acc[6] += __uint_as_float(v.w << 16);
    acc[7] += __uint_as_float(v.w & 0xffff0000u);
}

__device__ __forceinline__ unsigned pack2(float a, float b) {
    unsigned short ua = __builtin_bit_cast(unsigned short, __float2bfloat16(a));
    unsigned short ub = __builtin_bit_cast(unsigned short, __float2bfloat16(b));
    return (unsigned)ua | ((unsigned)ub << 16);
}

// ---------------- agg over COLS-col bf16 rows; L = COLS/8 lanes/node ----------------
template <int COLS, int L>
__global__ __launch_bounds__(THREADS) void agg_bf16_kernel(
        const __hip_bfloat16* __restrict__ S, const int* __restrict__ row_ptr,
        const int* __restrict__ col, const float* __restrict__ dis,
        __hip_bfloat16* __restrict__ out, int n) {
    static_assert(L * 8 == COLS, "");
    constexpr int stride = COLS / 8;       // uint4 per row
    int node = blockIdx.x * (THREADS / L) + threadIdx.x / L;
    if (node >= n) return;
    int lane = threadIdx.x % L;
    const uint4* S4 = reinterpret_cast<const uint4*>(S);

    float acc[8];
#pragma unroll
    for (int q = 0; q < 8; ++q) acc[q] = 0.f;
    acc8(acc, S4[(size_t)node * stride + lane]);   // self-loop term

    int s = row_ptr[node], e = row_ptr[node + 1];
    int p = s;
    for (; p + 8 <= e; p += 8) {
        int j[8];
#pragma unroll
        for (int q = 0; q < 8; ++q) j[q] = col[p + q];
        uint4 v[8];
#pragma unroll
        for (int q = 0; q < 8; ++q) v[q] = S4[(size_t)j[q] * stride + lane];
#pragma unroll
        for (int q = 0; q < 8; ++q) acc8(acc, v[q]);
    }
    for (; p + 2 <= e; p += 2) {
        int j0 = col[p], j1 = col[p + 1];
        uint4 v0 = S4[(size_t)j0 * stride + lane];
        uint4 v1 = S4[(size_t)j1 * stride + lane];
        acc8(acc, v0); acc8(acc, v1);
    }
    for (; p < e; ++p) acc8(acc, S4[(size_t)col[p] * stride + lane]);

    float d = dis[node];
    uint4 o;
    o.x = pack2(acc[0] * d, acc[1] * d);
    o.y = pack2(acc[2] * d, acc[3] * d);
    o.z = pack2(acc[4] * d, acc[5] * d);
    o.w = pack2(acc[6] * d, acc[7] * d);
    reinterpret_cast<uint4*>(out)[(size_t)node * stride + lane] = o;
}

// ---------------- layer-1 transform: [N,10]f32 @ [10,128] + b, relu, *dis -> bf16 ----------------
__global__ __launch_bounds__(THREADS) void transform1_kernel(
        const float* __restrict__ A0, const float* __restrict__ W,
        const float* __restrict__ b, const float* __restrict__ dis,
        __hip_bfloat16* __restrict__ out, int n) {
    int t = blockIdx.x * blockDim.x + threadIdx.x;
    if (t >= n * 128) return;
    int r = t >> 7;
    int c = t & 127;
    float acc = b[c];
#pragma unroll
    for (int k = 0; k < 10; ++k)
        acc = fmaf(A0[(size_t)r * 10 + k], W[k * 128 + c], acc);
    out[(size_t)r * 128 + c] = __float2bfloat16(fmaxf(acc, 0.f) * dis[r]);
}

// ---------------- MFMA transform v2: bf16 [N,K] @ WT[256][K] -> bf16 [N,256] ----------------
// Block = 4 waves. Wave w owns cols [w*64, w*64+64): B-frags preloaded ONCE
// into named registers. Grid-stride over 16-row tiles; next tile's A-frags
// prefetched into a second named buffer.
template <int K, bool SCALE>
__global__ __launch_bounds__(THREADS) void transform_mfma2_kernel(
        const __hip_bfloat16* __restrict__ A, const __hip_bfloat16* __restrict__ WT,
        const float* __restrict__ b, const float* __restrict__ dis,
        __hip_bfloat16* __restrict__ out, int n, int ntiles) {
    constexpr int KS = K / 32;             // 4 (K=128) or 8 (K=256)
    const int wave = threadIdx.x >> 6;
    const int lane = threadIdx.x & 63;
    const int lrow = lane & 15;
    const int lk8  = (lane >> 4) * 8;      // k-element offset within a 32-k step

    const uint4* WT4 = reinterpret_cast<const uint4*>(WT);
    bf16x8 bfr[4][KS];
    float bias[4];
#pragma unroll
    for (int ct = 0; ct < 4; ++ct) {
        int colc = wave * 64 + ct * 16 + lrow;
        bias[ct] = b[colc];
#pragma unroll
        for (int kk = 0; kk < KS; ++kk)
            bfr[ct][kk] = __builtin_bit_cast(
                bf16x8, WT4[((size_t)colc * K + kk * 32 + lk8) >> 3]);
    }

    const uint4* A4 = reinterpret_cast<const uint4*>(A);
    auto loadA = [&](int t, uint4* av) {
        int row = t * 16 + lrow;
        if (row >= n) row = n - 1;
#pragma unroll
        for (int kk = 0; kk < KS; ++kk)
            av[kk] = A4[((size_t)row * K + kk * 32 + lk8) >> 3];
    };

    uint4 aC[KS], aN[KS];
    int t = blockIdx.x;
    if (t < ntiles) loadA(t, aC);

    for (; t < ntiles; t += gridDim.x) {
        int tn = t + gridDim.x;
        if (tn < ntiles) loadA(tn, aN);    // prefetch next tile

        f32x4 acc[4];
#pragma unroll
        for (int ct = 0; ct < 4; ++ct) acc[ct] = (f32x4){0.f, 0.f, 0.f, 0.f};
#pragma unroll
        for (int kk = 0; kk < KS; ++kk) {
            bf16x8 af = __builtin_bit_cast(bf16x8, aC[kk]);
#pragma unroll
            for (int ct = 0; ct < 4; ++ct)
                acc[ct] = __builtin_amdgcn_mfma_f32_16x16x32_bf16(af, bfr[ct][kk], acc[ct], 0, 0, 0);
        }

        const int orow0 = t * 16 + (lane >> 4) * 4;
        float dv[4];
#pragma unroll
        for (int r = 0; r < 4; ++r) {
            int rr = orow0 + r;
            dv[r] = SCALE ? ((rr < n) ? dis[rr] : 0.f) : 1.f;
        }
#pragma unroll
        for (int ct = 0; ct < 4; ++ct) {
            int colc = wave * 64 + ct * 16 + lrow;
#pragma unroll
            for (int r = 0; r < 4; ++r) {
                int rr = orow0 + r;
                if (rr < n) {
                    float v = fmaxf(acc[ct][r] + bias[ct], 0.f);
                    if (SCALE) v *= dv[r];
                    out[(size_t)rr * 256 + colc] = __float2bfloat16(v);
                }
            }
        }
#pragma unroll
        for (int kk = 0; kk < KS; ++kk) aC[kk] = aN[kk];
    }
}

// ---------------- mean pool over sorted batch ranges (bf16 input) ----------------
__global__ __launch_bounds__(THREADS) void pool_kernel(
        const __hip_bfloat16* __restrict__ H, const int* __restrict__ goff,
        float* __restrict__ pooled) {
    int g = blockIdx.x;
    int c = threadIdx.x;
    int s = goff[g], e = goff[g + 1];
    float acc = 0.f;
    for (int r = s; r < e; ++r) acc += __bfloat162float(H[(size_t)r * 256 + c]);
    float cnt = (float)(e - s);
    pooled[(size_t)g * 256 + c] = acc / fmaxf(cnt, 1.0f);
}

// ---------------- heads ----------------
__global__ __launch_bounds__(128) void heads_kernel(
        const float* __restrict__ pooled,
        const float* __restrict__ Wmu, const float* __restrict__ bmu,
        const float* __restrict__ Wlv, const float* __restrict__ blv,
        float* __restrict__ out, int g_total) {
    __shared__ float p[256];
    int g = blockIdx.x;
    for (int k = threadIdx.x; k < 256; k += 128) p[k] = pooled[(size_t)g * 256 + k];
    __syncthreads();
    int c = threadIdx.x & 63;
    bool is_mu = threadIdx.x < 64;
    const float* W = is_mu ? Wmu : Wlv;
    const float* bb = is_mu ? bmu : blv;
    float acc = 0.f;
    for (int k = 0; k < 256; ++k) acc = fmaf(p[k], W[k * 64 + c], acc);
    float* o = is_mu ? (out + (size_t)g * 64) : (out + (size_t)g_total * 64 + (size_t)g * 64);
    o[c] = acc + bb[c];
}

extern "C" void kernel_launch(void* const* d_in, const int* in_sizes, int n_in,
                              void* d_out, int out_size, void* d_ws, size_t ws_size,
                              hipStream_t stream) {
    const float* x      = (const float*)d_in[0];
    const int*   eidx   = (const int*)d_in[1];
    const int*   batch  = (const int*)d_in[2];
    const float* W1  = (const float*)d_in[3];
    const float* b1  = (const float*)d_in[4];
    const float* W2  = (const float*)d_in[5];
    const float* b2  = (const float*)d_in[6];
    const float* W3  = (const float*)d_in[7];
    const float* b3  = (const float*)d_in[8];
    const float* Wmu = (const float*)d_in[9];
    const float* bmu = (const float*)d_in[10];
    const float* Wlv = (const float*)d_in[11];
    const float* blv = (const float*)d_in[12];
    float* out = (float*)d_out;

    const int N = in_sizes[0] / 10;
    const int E = in_sizes[1] / 2;
    const int G = out_size / 128;

    const int* src = eidx;       // edge_index[0]
    const int* dst = eidx + E;   // edge_index[1]

    // workspace carve-up (~122 MB)
    __hip_bfloat16* SA = (__hip_bfloat16*)d_ws;          // [N,256] bf16 ping
    __hip_bfloat16* SB = SA + (size_t)N * 256;           // [N,256] bf16 pong
    float* F0   = (float*)(SB + (size_t)N * 256);        // [N,10] scaled x
    float* B0   = F0 + (size_t)N * 10;                   // [N,10] agg out
    float* dis  = B0 + (size_t)N * 10;                   // [N]
    float* pooled = dis + N;                             // [G,256]
    __hip_bfloat16* W2T = (__hip_bfloat16*)(pooled + (size_t)G * 256); // [256][128]
    __hip_bfloat16* W3T = W2T + 256 * 128;               // [256][256]
    int* deg     = (int*)(W3T + 256 * 256);              // [N]
    int* row_ptr = deg + N;                              // [N+1]
    int* cursor  = row_ptr + N + 1;                      // [N]
    int* col     = cursor + N;                           // [E]
    int* gcnt    = col + E;                              // [G]
    int* goff    = gcnt + G;                             // [G+1]

    const int ntiles = (N + 15) / 16;

    // setup: deg=1, gcnt=0, W transposes (one launch)
    {
        int total = N + G + 128 * 256 + 256 * 256;
        setup_kernel<<<(total + THREADS - 1) / THREADS, THREADS, 0, stream>>>(
            deg, gcnt, W2, W2T, W3, W3T, N, G);
    }
    // histograms: indegree + graph sizes (one launch)
    {
        int total = E + N;
        hist_kernel<<<(total + THREADS - 1) / THREADS, THREADS, 0, stream>>>(
            dst, deg, E, batch, gcnt, N);
    }
    // scans: row_ptr (+cursor, +dis) and goff (one launch)
    scan_all_kernel<<<1, 1024, 0, stream>>>(deg, row_ptr, cursor, dis, N, gcnt, goff, G);
    // CSR fill (nt col store) + x*dis scale (one launch)
    {
        int total = E + N * 10;
        fill_scale_kernel<<<(total + THREADS - 1) / THREADS, THREADS, 0, stream>>>(
            src, dst, cursor, col, x, dis, F0, E, N * 10);
    }

    // layer 1: aggregate x*dis (10 f32 cols) then transform 10->128 -> bf16
    agg10_kernel<<<(N + 15) / 16, THREADS, 0, stream>>>(F0, row_ptr, col, dis, B0, N);
    transform1_kernel<<<((size_t)N * 128 + THREADS - 1) / THREADS, THREADS, 0, stream>>>(B0, W1, b1, dis, SA, N);

    // layer 2: aggregate S1 (128 bf16 cols) then MFMA transform 128->256 (*dis)
    agg_bf16_kernel<128, 16><<<(N + 15) / 16, THREADS, 0, stream>>>(SA, row_ptr, col, dis, SB, N);
    transform_mfma2_kernel<128, true><<<512, THREADS, 0, stream>>>(SB, W2T, b2, dis, SA, N, ntiles);

    // layer 3: aggregate S2 (256 bf16 cols) then MFMA transform 256->256
    agg_bf16_kernel<256, 32><<<(N + 7) / 8, THREADS, 0, stream>>>(SA, row_ptr, col, dis, SB, N);
    transform_mfma2_kernel<256, false><<<512, THREADS, 0, stream>>>(SB, W3T, b3, dis, SA, N, ntiles);

    // mean pool + heads
    pool_kernel<<<G, THREADS, 0, stream>>>(SA, goff, pooled);
    heads_kernel<<<G, 128, 0, stream>>>(pooled, Wmu, bmu, Wlv, blv, out, G);
}

// Round 6
// 648.701 us; speedup vs baseline: 1.0748x; 1.0748x over previous
//
#include <hip/hip_runtime.h>
#include <hip/hip_bf16.h>
#include <math.h>

// GraphEncoder: 3x GCNConv (relu) -> global_mean_pool -> two linear heads.
// N=100000, E=1600000, G=2048, feats 10->128->256->256->64(x2)
//
// Round-6 strategy:
//  - fill_csr: dst-sliced (8 passes) so the active col+cursor window (~0.85MB)
//    stays L2-resident -> dirty lines written back once, full. Round-5's nt
//    store REGRESSED (112MB HBM writes): nt bypasses L2 coalescing entirely.
//    Plain stores + slicing instead. (If still ~130us -> atomic-bound -> radix.)
//  - agg10 reads x and dis inline (drops scale0 kernel + F0 buffer).
//  - pool+heads fused, pooled vector lives in LDS.

#define THREADS 256

typedef __attribute__((ext_vector_type(8))) short bf16x8;
typedef __attribute__((ext_vector_type(4))) float f32x4;

// ---------------- fused setup: deg=1, gcnt=0, W2T, W3T ----------------
__global__ void setup_kernel(int* deg, int* gcnt,
                             const float* __restrict__ W2, __hip_bfloat16* __restrict__ W2T,
                             const float* __restrict__ W3, __hip_bfloat16* __restrict__ W3T,
                             int n, int g) {
    int i = blockIdx.x * blockDim.x + threadIdx.x;
    if (i < n) deg[i] = 1;                       // self-loop
    int r1 = i - n;
    if (r1 >= 0 && r1 < g) gcnt[r1] = 0;
    int r2 = i - n - g;
    if (r2 >= 0 && r2 < 128 * 256) {
        int k = r2 >> 8, c = r2 & 255;
        W2T[c * 128 + k] = __float2bfloat16(W2[r2]);
    }
    int r3 = i - n - g - 128 * 256;
    if (r3 >= 0 && r3 < 256 * 256) {
        int k = r3 >> 8, c = r3 & 255;
        W3T[c * 256 + k] = __float2bfloat16(W3[r3]);
    }
}

// ---------------- fused histograms: indegree + graph sizes ----------------
__global__ void hist_kernel(const int* __restrict__ dst, int* deg, int e,
                            const int* __restrict__ batch, int* gcnt, int n) {
    int i = blockIdx.x * blockDim.x + threadIdx.x;
    if (i < e) {
        atomicAdd(&deg[dst[i]], 1);
    } else {
        int j = i - e;
        if (j < n) atomicAdd(&gcnt[batch[j]], 1);
    }
}

// ---------------- fused scans ----------------
__device__ void scan_phase(const int* __restrict__ in, int* __restrict__ out,
                           int n, int sub, int* wsum,
                           int* __restrict__ cursor, float* __restrict__ dis) {
    int carry = 0;
    const int lane = threadIdx.x & 63;
    const int wid = threadIdx.x >> 6;
    for (int base = 0; base < n; base += 4096) {
        int i0 = base + threadIdx.x * 4;
        int v[4];
#pragma unroll
        for (int q = 0; q < 4; ++q) {
            int i = i0 + q;
            v[q] = (i < n) ? (in[i] - sub) : 0;
        }
        int tsum = v[0] + v[1] + v[2] + v[3];
        int incl = tsum;
#pragma unroll
        for (int off = 1; off < 64; off <<= 1) {
            int t = __shfl_up(incl, off, 64);
            if (lane >= off) incl += t;
        }
        if (lane == 63) wsum[wid] = incl;
        __syncthreads();
        int wbase = 0;
        for (int w = 0; w < wid; ++w) wbase += wsum[w];
        int pos = incl - tsum + wbase + carry;
#pragma unroll
        for (int q = 0; q < 4; ++q) {
            int i = i0 + q;
            if (i < n) {
                out[i] = pos;
                if (cursor) cursor[i] = pos;
                if (dis) dis[i] = rsqrtf((float)(v[q] + sub));
            }
            pos += v[q];
        }
        int tot = 0;
        for (int w = 0; w < 16; ++w) tot += wsum[w];
        carry += tot;
        __syncthreads();
    }
    if (threadIdx.x == 0) out[n] = carry;
}

__global__ __launch_bounds__(1024) void scan_all_kernel(
        const int* deg, int* row_ptr, int* cursor, float* dis, int n,
        const int* gcnt, int* goff, int g) {
    __shared__ int wsum[16];
    scan_phase(deg, row_ptr, n, 1, wsum, cursor, dis);   // indeg scan + dis + cursor
    __syncthreads();
    scan_phase(gcnt, goff, g, 0, wsum, nullptr, nullptr);
}

// ---------------- dst-sliced CSR fill ----------------
// 8 sequential slices over the dst range keep the active col+cursor window
// (~0.85MB) L2-resident so dirty lines are written back once, full.
__global__ __launch_bounds__(THREADS) void fill_csr_kernel(
        const int* __restrict__ src, const int* __restrict__ dst,
        int* cursor, int* __restrict__ col, int e, int n) {
    const int nslice = 8;
    const int sliceSize = (n + nslice - 1) / nslice;
    const int tid = blockIdx.x * blockDim.x + threadIdx.x;
    const int nthr = gridDim.x * blockDim.x;
    for (int s = 0; s < nslice; ++s) {
        const int lo = s * sliceSize;
        const int hi = lo + sliceSize;
        for (int i = tid; i < e; i += nthr) {
            int d = dst[i];
            if (d >= lo && d < hi) {
                int pos = atomicAdd(&cursor[d], 1);
                col[pos] = src[i];
            }
        }
    }
}

// ---------------- agg over 10-col f32 rows, inline x*dis (16 lanes/node) ----------------
__global__ __launch_bounds__(THREADS) void agg10_kernel(
        const float* __restrict__ x, const int* __restrict__ row_ptr,
        const int* __restrict__ col, const float* __restrict__ dis,
        float* __restrict__ out, int n) {
    int node = blockIdx.x * 16 + threadIdx.x / 16;
    if (node >= n) return;
    int lane = threadIdx.x % 16;
    bool act = lane < 10;
    float dn = dis[node];
    float acc = act ? x[(size_t)node * 10 + lane] * dn : 0.f;
    int s = row_ptr[node], e = row_ptr[node + 1];
    int p = s;
    for (; p + 4 <= e; p += 4) {
        int j[4];
#pragma unroll
        for (int q = 0; q < 4; ++q) j[q] = col[p + q];
        float v[4];
#pragma unroll
        for (int q = 0; q < 4; ++q)
            v[q] = act ? x[(size_t)j[q] * 10 + lane] * dis[j[q]] : 0.f;
        acc += v[0] + v[1] + v[2] + v[3];
    }
    for (; p < e; ++p) {
        int j = col[p];
        if (act) acc += x[(size_t)j * 10 + lane] * dis[j];
    }
    if (act) out[(size_t)node * 10 + lane] = acc * dn;
}

// ---------------- bf16 helpers ----------------
__device__ __forceinline__ void acc8(float* acc, uint4 v) {
    acc[0] += __uint_as_float(v.x << 16);
    acc[1] += __uint_as_float(v.x & 0xffff0000u);
    acc[2] += __uint_as_float(v.y << 16);
    acc[3] += __uint_as_float(v.y & 0xffff0000u);
    acc[4] += __uint_as_float(v.z << 16);
    acc[5] += __uint_as_float(v.z & 0xffff0000u);
    acc[6] += __uint_as_float(v.w << 16);
    acc[7] += __uint_as_float(v.w & 0xffff0000u);
}

__device__ __forceinline__ unsigned pack2(float a, float b) {
    unsigned short ua = __builtin_bit_cast(unsigned short, __float2bfloat16(a));
    unsigned short ub = __builtin_bit_cast(unsigned short, __float2bfloat16(b));
    return (unsigned)ua | ((unsigned)ub << 16);
}

// ---------------- agg over COLS-col bf16 rows; L = COLS/8 lanes/node ----------------
template <int COLS, int L>
__global__ __launch_bounds__(THREADS) void agg_bf16_kernel(
        const __hip_bfloat16* __restrict__ S, const int* __restrict__ row_ptr,
        const int* __restrict__ col, const float* __restrict__ dis,
        __hip_bfloat16* __restrict__ out, int n) {
    static_assert(L * 8 == COLS, "");
    constexpr int stride = COLS / 8;       // uint4 per row
    int node = blockIdx.x * (THREADS / L) + threadIdx.x / L;
    if (node >= n) return;
    int lane = threadIdx.x % L;
    const uint4* S4 = reinterpret_cast<const uint4*>(S);

    float acc[8];
#pragma unroll
    for (int q = 0; q < 8; ++q) acc[q] = 0.f;
    acc8(acc, S4[(size_t)node * stride + lane]);   // self-loop term

    int s = row_ptr[node], e = row_ptr[node + 1];
    int p = s;
    for (; p + 8 <= e; p += 8) {
        int j[8];
#pragma unroll
        for (int q = 0; q < 8; ++q) j[q] = col[p + q];
        uint4 v[8];
#pragma unroll
        for (int q = 0; q < 8; ++q) v[q] = S4[(size_t)j[q] * stride + lane];
#pragma unroll
        for (int q = 0; q < 8; ++q) acc8(acc, v[q]);
    }
    for (; p + 2 <= e; p += 2) {
        int j0 = col[p], j1 = col[p + 1];
        uint4 v0 = S4[(size_t)j0 * stride + lane];
        uint4 v1 = S4[(size_t)j1 * stride + lane];
        acc8(acc, v0); acc8(acc, v1);
    }
    for (; p < e; ++p) acc8(acc, S4[(size_t)col[p] * stride + lane]);

    float d = dis[node];
    uint4 o;
    o.x = pack2(acc[0] * d, acc[1] * d);
    o.y = pack2(acc[2] * d, acc[3] * d);
    o.z = pack2(acc[4] * d, acc[5] * d);
    o.w = pack2(acc[6] * d, acc[7] * d);
    reinterpret_cast<uint4*>(out)[(size_t)node * stride + lane] = o;
}

// ---------------- layer-1 transform: [N,10]f32 @ [10,128] + b, relu, *dis -> bf16 ----------------
__global__ __launch_bounds__(THREADS) void transform1_kernel(
        const float* __restrict__ A0, const float* __restrict__ W,
        const float* __restrict__ b, const float* __restrict__ dis,
        __hip_bfloat16* __restrict__ out, int n) {
    int t = blockIdx.x * blockDim.x + threadIdx.x;
    if (t >= n * 128) return;
    int r = t >> 7;
    int c = t & 127;
    float acc = b[c];
#pragma unroll
    for (int k = 0; k < 10; ++k)
        acc = fmaf(A0[(size_t)r * 10 + k], W[k * 128 + c], acc);
    out[(size_t)r * 128 + c] = __float2bfloat16(fmaxf(acc, 0.f) * dis[r]);
}

// ---------------- MFMA transform v2: bf16 [N,K] @ WT[256][K] -> bf16 [N,256] ----------------
template <int K, bool SCALE>
__global__ __launch_bounds__(THREADS) void transform_mfma2_kernel(
        const __hip_bfloat16* __restrict__ A, const __hip_bfloat16* __restrict__ WT,
        const float* __restrict__ b, const float* __restrict__ dis,
        __hip_bfloat16* __restrict__ out, int n, int ntiles) {
    constexpr int KS = K / 32;             // 4 (K=128) or 8 (K=256)
    const int wave = threadIdx.x >> 6;
    const int lane = threadIdx.x & 63;
    const int lrow = lane & 15;
    const int lk8  = (lane >> 4) * 8;      // k-element offset within a 32-k step

    const uint4* WT4 = reinterpret_cast<const uint4*>(WT);
    bf16x8 bfr[4][KS];
    float bias[4];
#pragma unroll
    for (int ct = 0; ct < 4; ++ct) {
        int colc = wave * 64 + ct * 16 + lrow;
        bias[ct] = b[colc];
#pragma unroll
        for (int kk = 0; kk < KS; ++kk)
            bfr[ct][kk] = __builtin_bit_cast(
                bf16x8, WT4[((size_t)colc * K + kk * 32 + lk8) >> 3]);
    }

    const uint4* A4 = reinterpret_cast<const uint4*>(A);
    auto loadA = [&](int t, uint4* av) {
        int row = t * 16 + lrow;
        if (row >= n) row = n - 1;
#pragma unroll
        for (int kk = 0; kk < KS; ++kk)
            av[kk] = A4[((size_t)row * K + kk * 32 + lk8) >> 3];
    };

    uint4 aC[KS], aN[KS];
    int t = blockIdx.x;
    if (t < ntiles) loadA(t, aC);

    for (; t < ntiles; t += gridDim.x) {
        int tn = t + gridDim.x;
        if (tn < ntiles) loadA(tn, aN);    // prefetch next tile

        f32x4 acc[4];
#pragma unroll
        for (int ct = 0; ct < 4; ++ct) acc[ct] = (f32x4){0.f, 0.f, 0.f, 0.f};
#pragma unroll
        for (int kk = 0; kk < KS; ++kk) {
            bf16x8 af = __builtin_bit_cast(bf16x8, aC[kk]);
#pragma unroll
            for (int ct = 0; ct < 4; ++ct)
                acc[ct] = __builtin_amdgcn_mfma_f32_16x16x32_bf16(af, bfr[ct][kk], acc[ct], 0, 0, 0);
        }

        const int orow0 = t * 16 + (lane >> 4) * 4;
        float dv[4];
#pragma unroll
        for (int r = 0; r < 4; ++r) {
            int rr = orow0 + r;
            dv[r] = SCALE ? ((rr < n) ? dis[rr] : 0.f) : 1.f;
        }
#pragma unroll
        for (int ct = 0; ct < 4; ++ct) {
            int colc = wave * 64 + ct * 16 + lrow;
#pragma unroll
            for (int r = 0; r < 4; ++r) {
                int rr = orow0 + r;
                if (rr < n) {
                    float v = fmaxf(acc[ct][r] + bias[ct], 0.f);
                    if (SCALE) v *= dv[r];
                    out[(size_t)rr * 256 + colc] = __float2bfloat16(v);
                }
            }
        }
#pragma unroll
        for (int kk = 0; kk < KS; ++kk) aC[kk] = aN[kk];
    }
}

// ---------------- fused mean-pool + heads (pooled in LDS) ----------------
__global__ __launch_bounds__(THREADS) void pool_heads_kernel(
        const __hip_bfloat16* __restrict__ H, const int* __restrict__ goff,
        const float* __restrict__ Wmu, const float* __restrict__ bmu,
        const float* __restrict__ Wlv, const float* __restrict__ blv,
        float* __restrict__ out, int g_total) {
    __shared__ float p[256];
    int g = blockIdx.x;
    int c = threadIdx.x;
    int s = goff[g], e = goff[g + 1];
    float acc = 0.f;
    for (int r = s; r < e; ++r) acc += __bfloat162float(H[(size_t)r * 256 + c]);
    p[c] = acc / fmaxf((float)(e - s), 1.0f);
    __syncthreads();
    if (threadIdx.x < 128) {
        int cc = threadIdx.x & 63;
        bool is_mu = threadIdx.x < 64;
        const float* W = is_mu ? Wmu : Wlv;
        const float* bb = is_mu ? bmu : blv;
        float a = 0.f;
        for (int k = 0; k < 256; ++k) a = fmaf(p[k], W[k * 64 + cc], a);
        float* o = is_mu ? (out + (size_t)g * 64)
                         : (out + (size_t)g_total * 64 + (size_t)g * 64);
        o[cc] = a + bb[cc];
    }
}

extern "C" void kernel_launch(void* const* d_in, const int* in_sizes, int n_in,
                              void* d_out, int out_size, void* d_ws, size_t ws_size,
                              hipStream_t stream) {
    const float* x      = (const float*)d_in[0];
    const int*   eidx   = (const int*)d_in[1];
    const int*   batch  = (const int*)d_in[2];
    const float* W1  = (const float*)d_in[3];
    const float* b1  = (const float*)d_in[4];
    const float* W2  = (const float*)d_in[5];
    const float* b2  = (const float*)d_in[6];
    const float* W3  = (const float*)d_in[7];
    const float* b3  = (const float*)d_in[8];
    const float* Wmu = (const float*)d_in[9];
    const float* bmu = (const float*)d_in[10];
    const float* Wlv = (const float*)d_in[11];
    const float* blv = (const float*)d_in[12];
    float* out = (float*)d_out;

    const int N = in_sizes[0] / 10;
    const int E = in_sizes[1] / 2;
    const int G = out_size / 128;

    const int* src = eidx;       // edge_index[0]
    const int* dst = eidx + E;   // edge_index[1]

    // workspace carve-up (~118 MB)
    __hip_bfloat16* SA = (__hip_bfloat16*)d_ws;          // [N,256] bf16 ping
    __hip_bfloat16* SB = SA + (size_t)N * 256;           // [N,256] bf16 pong
    float* B0   = (float*)(SB + (size_t)N * 256);        // [N,10] agg out
    float* dis  = B0 + (size_t)N * 10;                   // [N]
    __hip_bfloat16* W2T = (__hip_bfloat16*)(dis + N);    // [256][128]
    __hip_bfloat16* W3T = W2T + 256 * 128;               // [256][256]
    int* deg     = (int*)(W3T + 256 * 256);              // [N]
    int* row_ptr = deg + N;                              // [N+1]
    int* cursor  = row_ptr + N + 1;                      // [N]
    int* col     = cursor + N;                           // [E]
    int* gcnt    = col + E;                              // [G]
    int* goff    = gcnt + G;                             // [G+1]

    const int ntiles = (N + 15) / 16;

    // setup: deg=1, gcnt=0, W transposes
    {
        int total = N + G + 128 * 256 + 256 * 256;
        setup_kernel<<<(total + THREADS - 1) / THREADS, THREADS, 0, stream>>>(
            deg, gcnt, W2, W2T, W3, W3T, N, G);
    }
    // histograms: indegree + graph sizes
    {
        int total = E + N;
        hist_kernel<<<(total + THREADS - 1) / THREADS, THREADS, 0, stream>>>(
            dst, deg, E, batch, gcnt, N);
    }
    // scans: row_ptr (+cursor, +dis) and goff
    scan_all_kernel<<<1, 1024, 0, stream>>>(deg, row_ptr, cursor, dis, N, gcnt, goff, G);
    // dst-sliced CSR fill (all-resident grid, slices advance in phase)
    fill_csr_kernel<<<2048, THREADS, 0, stream>>>(src, dst, cursor, col, E, N);

    // layer 1: aggregate x*dis (10 f32 cols, inline) then transform 10->128 -> bf16
    agg10_kernel<<<(N + 15) / 16, THREADS, 0, stream>>>(x, row_ptr, col, dis, B0, N);
    transform1_kernel<<<((size_t)N * 128 + THREADS - 1) / THREADS, THREADS, 0, stream>>>(B0, W1, b1, dis, SA, N);

    // layer 2: aggregate S1 (128 bf16 cols) then MFMA transform 128->256 (*dis)
    agg_bf16_kernel<128, 16><<<(N + 15) / 16, THREADS, 0, stream>>>(SA, row_ptr, col, dis, SB, N);
    transform_mfma2_kernel<128, true><<<512, THREADS, 0, stream>>>(SB, W2T, b2, dis, SA, N, ntiles);

    // layer 3: aggregate S2 (256 bf16 cols) then MFMA transform 256->256
    agg_bf16_kernel<256, 32><<<(N + 7) / 8, THREADS, 0, stream>>>(SA, row_ptr, col, dis, SB, N);
    transform_mfma2_kernel<256, false><<<512, THREADS, 0, stream>>>(SB, W3T, b3, dis, SA, N, ntiles);

    // fused mean pool + heads
    pool_heads_kernel<<<G, THREADS, 0, stream>>>(SA, goff, Wmu, bmu, Wlv, blv, out, G);
}